// Round 9
// baseline (1207.955 us; speedup 1.0000x reference)
//
#include <hip/hip_runtime.h>
#include <hip/hip_bf16.h>

// Problem constants
#define B_    256
#define K_    64
#define D_    256
#define T_    8
#define NROW  (B_*K_)

typedef short short8v __attribute__((ext_vector_type(8)));
typedef float f32x4  __attribute__((ext_vector_type(4)));

// ---------- device helpers ----------
__device__ __forceinline__ float fexp2(float x) { return __builtin_amdgcn_exp2f(x); }
__device__ __forceinline__ float flog2(float x) { return __builtin_amdgcn_logf(x); }

__device__ __forceinline__ float sigmoid_f(float x) {
  return 1.f / (1.f + fexp2(x * -1.4426950408889634f));
}
__device__ __forceinline__ float tanh_fast(float x) {
  float xc = fminf(fmaxf(x, -30.f), 30.f);
  float t = fexp2(xc * 2.8853900817779268f);   // e^(2x)
  return (t - 1.f) / (t + 1.f);
}
__device__ __forceinline__ float gelu_f(float x) {
  return 0.5f * x * (1.f + erff(x * 0.70710678118654752440f));
}
__device__ __forceinline__ unsigned short f2bf(float x) {
  __hip_bfloat16 h = __float2bfloat16(x);
  return *reinterpret_cast<unsigned short*>(&h);
}
__device__ __forceinline__ float bfss(unsigned short s) {
  return __uint_as_float(((unsigned int)s) << 16);
}
__device__ __forceinline__ float muS_f(float x, float a2, float b2) {
  float mid = 0.5f * (a2 + b2);
  float inv = 1.f / (b2 - a2 + 1e-12f);
  if (x > b2)  return 1.f;
  if (x > mid) { float u = (b2 - x) * inv; return 1.f - 2.f * u * u; }
  if (x > a2)  { float u = (x - a2) * inv; return 2.f * u * u; }
  return 0.f;
}
__device__ __forceinline__ float pow_abs(float z, float e2b) {
  return fexp2(e2b * flog2(fabsf(z)));
}
__device__ __forceinline__ float defuzz_one(float rb_, float rs_, float ab, float bb) {
  float e2b = 2.f * bb;
  float inv_ab = 1.f / ab;
  float cb = 4.f * tanh_fast(rb_);
  float num = 0.f, den = 0.f;
  #pragma unroll
  for (int j = 0; j < 41; ++j) {
    float gj = -4.f + 0.2f * (float)j;
    float mu = 1.f / (1.f + pow_abs((gj - cb) * inv_ab, e2b));
    num += gj * mu; den += mu;
  }
  float cenb = num / (den + 1e-12f);
  float cs = 4.f * tanh_fast(rs_);
  float as_ = fminf(fmaxf(cs - 1.f, -4.f), 4.f);
  float bs_ = fminf(fmaxf(cs + 1.f, -4.f), 4.f);
  num = 0.f; den = 0.f;
  {
    float mid = 0.5f * (as_ + bs_);
    float inv = 1.f / (bs_ - as_ + 1e-12f);
    #pragma unroll
    for (int j = 0; j < 41; ++j) {
      float gj = -4.f + 0.2f * (float)j;
      float mu;
      if (gj > bs_)      mu = 1.f;
      else if (gj > mid) { float u = (bs_ - gj) * inv; mu = 1.f - 2.f * u * u; }
      else if (gj > as_) { float u = (gj - as_) * inv; mu = 2.f * u * u; }
      else               mu = 0.f;
      num += gj * mu; den += mu;
    }
  }
  float cens = num / (den + 1e-12f);
  return 0.5f * cenb + 0.5f * cens;
}

// ---------- one-time: weight transposes / bf16 conversions ----------
__global__ __launch_bounds__(256) void k_convert(
    const float* __restrict__ W1, const float* __restrict__ Vf, const float* __restrict__ Vi,
    const float* __restrict__ W2, const float* __restrict__ FT,
    const float* __restrict__ WkI, const float* __restrict__ WkG,
    unsigned short* __restrict__ B1t, unsigned short* __restrict__ W2t,
    unsigned short* __restrict__ FTbf,
    float* __restrict__ WkIt, float* __restrict__ WkGt)
{
  int idx = blockIdx.x * 256 + threadIdx.x;
  if (idx < 262144) {
    int n = idx >> 8, k = idx & 255;
    float v = (n < 512) ? W1[(size_t)k*512 + n]
            : (n < 768) ? Vf[(size_t)k*256 + (n-512)]
                        : Vi[(size_t)k*256 + (n-768)];
    B1t[idx] = f2bf(v);
  } else if (idx < 393216) {
    int j = idx - 262144;
    int n = j >> 9, k = j & 511;
    W2t[j] = f2bf(W2[(size_t)k*256 + n]);
  } else if (idx < 409600) {
    int j = idx - 393216;
    FTbf[j] = f2bf(FT[j]);
  } else if (idx < 475136) {
    int j = idx - 409600;
    int k = j >> 8, n = j & 255;
    WkIt[j] = WkI[(size_t)n*256 + k];
  } else if (idx < 540672) {
    int j = idx - 475136;
    int k = j >> 8, n = j & 255;
    WkGt[j] = WkG[(size_t)n*256 + k];
  }
}

// ---------- precompute stage 1: lr/g linear + fuzzify ----------
__global__ __launch_bounds__(256) void k_pre_lin(
    const float* __restrict__ wsi, const float* __restrict__ gen,
    const float* __restrict__ W_lr, const float* __restrict__ b_lr,
    const float* __restrict__ W_g,  const float* __restrict__ b_g,
    const float* __restrict__ a_p,  const float* __restrict__ b_p,
    float* __restrict__ lrf, float* __restrict__ gf)
{
  int g_ix = blockIdx.x;
  int half = g_ix >> 4, tile = g_ix & 15;
  int bx = tile & 3, by = tile >> 2;
  int n0 = bx * 64, m0 = by * 64;
  const float* A    = half ? gen  : wsi;
  const float* Bm   = half ? W_g  : W_lr;
  const float* bias = half ? b_g  : b_lr;
  float* outp       = half ? gf   : lrf;
  int KK            = half ? 512  : 1024;
  float ab = fmaxf(a_p[0], 0.001f), bb = fmaxf(b_p[0], 0.001f);
  float e2b = 2.f * bb, inv_ab = 1.f / ab;

  __shared__ float As[16][64];
  __shared__ float Bs[16][64];
  int tid = threadIdx.x, tx = tid & 15, ty = tid >> 4;
  float acc[4][4] = {};
  int am = tid >> 2, ak = (tid & 3) * 4;
  int bk = tid >> 4, bn = (tid & 15) * 4;
  const float* arow = A + (size_t)(m0 + am) * KK;
  for (int k0 = 0; k0 < KK; k0 += 16) {
    float4 av = *(const float4*)(arow + k0 + ak);
    As[ak+0][am] = av.x; As[ak+1][am] = av.y; As[ak+2][am] = av.z; As[ak+3][am] = av.w;
    *(float4*)&Bs[bk][bn] = *(const float4*)(Bm + (size_t)(k0 + bk) * 256 + n0 + bn);
    __syncthreads();
    #pragma unroll
    for (int kk = 0; kk < 16; ++kk) {
      float a0 = As[kk][ty*4+0], a1 = As[kk][ty*4+1], a2 = As[kk][ty*4+2], a3 = As[kk][ty*4+3];
      float b0 = Bs[kk][tx*4+0], b1 = Bs[kk][tx*4+1], b2 = Bs[kk][tx*4+2], b3 = Bs[kk][tx*4+3];
      acc[0][0]=fmaf(a0,b0,acc[0][0]); acc[0][1]=fmaf(a0,b1,acc[0][1]); acc[0][2]=fmaf(a0,b2,acc[0][2]); acc[0][3]=fmaf(a0,b3,acc[0][3]);
      acc[1][0]=fmaf(a1,b0,acc[1][0]); acc[1][1]=fmaf(a1,b1,acc[1][1]); acc[1][2]=fmaf(a1,b2,acc[1][2]); acc[1][3]=fmaf(a1,b3,acc[1][3]);
      acc[2][0]=fmaf(a2,b0,acc[2][0]); acc[2][1]=fmaf(a2,b1,acc[2][1]); acc[2][2]=fmaf(a2,b2,acc[2][2]); acc[2][3]=fmaf(a2,b3,acc[2][3]);
      acc[3][0]=fmaf(a3,b0,acc[3][0]); acc[3][1]=fmaf(a3,b1,acc[3][1]); acc[3][2]=fmaf(a3,b2,acc[3][2]); acc[3][3]=fmaf(a3,b3,acc[3][3]);
    }
    __syncthreads();
  }
  #pragma unroll
  for (int i = 0; i < 4; ++i) {
    int row = m0 + ty*4 + i;
    #pragma unroll
    for (int j = 0; j < 4; ++j) {
      int col = n0 + tx*4 + j;
      float v = acc[i][j] + bias[col];
      float xs = 4.f * tanh_fast(v * 0.25f);
      outp[(size_t)row*512 + col]       = 1.f / (1.f + pow_abs(xs * inv_ab, e2b));
      outp[(size_t)row*512 + col + 256] = muS_f(xs, -1.f, 1.f);
    }
  }
}

// ---------- precompute stage 2: QI = lrf@WqI, QG = gf@WqG ----------
__global__ __launch_bounds__(256) void k_pre_q(
    const float* __restrict__ lrf, const float* __restrict__ gf,
    const float* __restrict__ WqI, const float* __restrict__ WqG,
    float* __restrict__ QI, float* __restrict__ QG)
{
  int g_ix = blockIdx.x;
  int half = g_ix >> 4, tile = g_ix & 15;
  int bx = tile & 3, by = tile >> 2;
  int n0 = bx * 64, m0 = by * 64;
  const float* A  = half ? gf  : lrf;
  const float* Bm = half ? WqG : WqI;
  float* outp     = half ? QG  : QI;

  __shared__ float As[16][64];
  __shared__ float Bs[16][64];
  int tid = threadIdx.x, tx = tid & 15, ty = tid >> 4;
  float acc[4][4] = {};
  int am = tid >> 2, ak = (tid & 3) * 4;
  int bk = tid >> 4, bn = (tid & 15) * 4;
  const float* arow = A + (size_t)(m0 + am) * 512;
  for (int k0 = 0; k0 < 512; k0 += 16) {
    float4 av = *(const float4*)(arow + k0 + ak);
    As[ak+0][am] = av.x; As[ak+1][am] = av.y; As[ak+2][am] = av.z; As[ak+3][am] = av.w;
    *(float4*)&Bs[bk][bn] = *(const float4*)(Bm + (size_t)(k0 + bk) * 256 + n0 + bn);
    __syncthreads();
    #pragma unroll
    for (int kk = 0; kk < 16; ++kk) {
      float a0 = As[kk][ty*4+0], a1 = As[kk][ty*4+1], a2 = As[kk][ty*4+2], a3 = As[kk][ty*4+3];
      float b0 = Bs[kk][tx*4+0], b1 = Bs[kk][tx*4+1], b2 = Bs[kk][tx*4+2], b3 = Bs[kk][tx*4+3];
      acc[0][0]=fmaf(a0,b0,acc[0][0]); acc[0][1]=fmaf(a0,b1,acc[0][1]); acc[0][2]=fmaf(a0,b2,acc[0][2]); acc[0][3]=fmaf(a0,b3,acc[0][3]);
      acc[1][0]=fmaf(a1,b0,acc[1][0]); acc[1][1]=fmaf(a1,b1,acc[1][1]); acc[1][2]=fmaf(a1,b2,acc[1][2]); acc[1][3]=fmaf(a1,b3,acc[1][3]);
      acc[2][0]=fmaf(a2,b0,acc[2][0]); acc[2][1]=fmaf(a2,b1,acc[2][1]); acc[2][2]=fmaf(a2,b2,acc[2][2]); acc[2][3]=fmaf(a2,b3,acc[2][3]);
      acc[3][0]=fmaf(a3,b0,acc[3][0]); acc[3][1]=fmaf(a3,b1,acc[3][1]); acc[3][2]=fmaf(a3,b2,acc[3][2]); acc[3][3]=fmaf(a3,b3,acc[3][3]);
    }
    __syncthreads();
  }
  #pragma unroll
  for (int i = 0; i < 4; ++i) {
    float4 v = make_float4(acc[i][0], acc[i][1], acc[i][2], acc[i][3]);
    *(float4*)(outp + (size_t)(m0 + ty*4 + i) * 256 + n0 + tx*4) = v;
  }
}

// ---------- precompute stage 3: qIp = QI@WkIt, qGp = QG@WkGt ----------
__global__ __launch_bounds__(256) void k_pre_qp(
    const float* __restrict__ QI, const float* __restrict__ QG,
    const float* __restrict__ WkIt, const float* __restrict__ WkGt,
    float* __restrict__ qIp, float* __restrict__ qGp)
{
  int g_ix = blockIdx.x;
  int half = g_ix >> 4, tile = g_ix & 15;
  int bx = tile & 3, by = tile >> 2;
  int n0 = bx * 64, m0 = by * 64;
  const float* A  = half ? QG   : QI;
  const float* Bm = half ? WkGt : WkIt;
  float* outp     = half ? qGp  : qIp;

  __shared__ float As[16][64];
  __shared__ float Bs[16][64];
  int tid = threadIdx.x, tx = tid & 15, ty = tid >> 4;
  float acc[4][4] = {};
  int am = tid >> 2, ak = (tid & 3) * 4;
  int bk = tid >> 4, bn = (tid & 15) * 4;
  const float* arow = A + (size_t)(m0 + am) * 256;
  for (int k0 = 0; k0 < 256; k0 += 16) {
    float4 av = *(const float4*)(arow + k0 + ak);
    As[ak+0][am] = av.x; As[ak+1][am] = av.y; As[ak+2][am] = av.z; As[ak+3][am] = av.w;
    *(float4*)&Bs[bk][bn] = *(const float4*)(Bm + (size_t)(k0 + bk) * 256 + n0 + bn);
    __syncthreads();
    #pragma unroll
    for (int kk = 0; kk < 16; ++kk) {
      float a0 = As[kk][ty*4+0], a1 = As[kk][ty*4+1], a2 = As[kk][ty*4+2], a3 = As[kk][ty*4+3];
      float b0 = Bs[kk][tx*4+0], b1 = Bs[kk][tx*4+1], b2 = Bs[kk][tx*4+2], b3 = Bs[kk][tx*4+3];
      acc[0][0]=fmaf(a0,b0,acc[0][0]); acc[0][1]=fmaf(a0,b1,acc[0][1]); acc[0][2]=fmaf(a0,b2,acc[0][2]); acc[0][3]=fmaf(a0,b3,acc[0][3]);
      acc[1][0]=fmaf(a1,b0,acc[1][0]); acc[1][1]=fmaf(a1,b1,acc[1][1]); acc[1][2]=fmaf(a1,b2,acc[1][2]); acc[1][3]=fmaf(a1,b3,acc[1][3]);
      acc[2][0]=fmaf(a2,b0,acc[2][0]); acc[2][1]=fmaf(a2,b1,acc[2][1]); acc[2][2]=fmaf(a2,b2,acc[2][2]); acc[2][3]=fmaf(a2,b3,acc[2][3]);
      acc[3][0]=fmaf(a3,b0,acc[3][0]); acc[3][1]=fmaf(a3,b1,acc[3][1]); acc[3][2]=fmaf(a3,b2,acc[3][2]); acc[3][3]=fmaf(a3,b3,acc[3][3]);
    }
    __syncthreads();
  }
  #pragma unroll
  for (int i = 0; i < 4; ++i) {
    float4 v = make_float4(acc[i][0], acc[i][1], acc[i][2], acc[i][3]);
    *(float4*)(outp + (size_t)(m0 + ty*4 + i) * 256 + n0 + tx*4) = v;
  }
}

// ---------- per step: ftbar (scores+softmax+weighted-sum), one block per batch ----------
__global__ __launch_bounds__(256) void k_ftbar(
    const unsigned short* __restrict__ Fb_all, int bcast,
    const float* __restrict__ qIp, const float* __restrict__ qGp,
    float* __restrict__ ftbI, float* __restrict__ ftbG)
{
  __shared__ __align__(16) char smem[38912];
  int b = blockIdx.x, t = threadIdx.x;
  short* Fs  = (short*)smem;                  // [64][264] bf16
  float* qv  = (float*)(smem + 33792);        // [512]
  float* red = (float*)(smem + 35840);        // [512]
  float* prl = (float*)(smem + 37888);        // p [128]

  const unsigned short* Fsrc = bcast ? Fb_all : (Fb_all + (size_t)b * K_ * D_);
  #pragma unroll
  for (int i = 0; i < 8; ++i) {
    int sidx = (i * 256 + t) * 8;
    int row = sidx >> 8, col = sidx & 255;
    *(float4*)&Fs[row * 264 + col] = *(const float4*)&Fsrc[sidx];
  }
  qv[t]       = qIp[(size_t)b*256 + t];
  qv[256 + t] = qGp[(size_t)b*256 + t];
  __syncthreads();
  {
    int k = t & 63, part = t >> 6;
    const unsigned int* frow = (const unsigned int*)&Fs[k * 264 + part * 64];
    const float* q0 = qv + part * 64;
    const float* q1 = qv + 256 + part * 64;
    float s0 = 0.f, s1 = 0.f;
    #pragma unroll
    for (int d2 = 0; d2 < 32; ++d2) {
      unsigned int pr = frow[d2];
      float f0 = __uint_as_float(pr << 16);
      float f1 = __uint_as_float(pr & 0xffff0000u);
      s0 = fmaf(f1, q0[2*d2+1], fmaf(f0, q0[2*d2], s0));
      s1 = fmaf(f1, q1[2*d2+1], fmaf(f0, q1[2*d2], s1));
    }
    red[t] = s0; red[256 + t] = s1;
  }
  __syncthreads();
  if (t < 128) {
    int which = t >> 6, kk = t & 63;
    const float* rp = red + which * 256;
    float s = (rp[kk] + rp[64+kk] + rp[128+kk] + rp[192+kk]) * (1.f/16.f);
    float m = s;
    for (int off = 32; off; off >>= 1) m = fmaxf(m, __shfl_xor(m, off, 64));
    float e = fexp2((s - m) * 1.4426950408889634f);
    float sum = e;
    for (int off = 32; off; off >>= 1) sum += __shfl_xor(sum, off, 64);
    prl[which * 64 + kk] = e / sum;
  }
  __syncthreads();
  {
    float f0 = 0.f, f1 = 0.f;
    #pragma unroll 8
    for (int kk = 0; kk < 64; ++kk) {
      float fv = bfss((unsigned short)Fs[kk * 264 + t]);
      f0 = fmaf(prl[kk],      fv, f0);
      f1 = fmaf(prl[64 + kk], fv, f1);
    }
    ftbI[(size_t)b*256 + t] = f0;
    ftbG[(size_t)b*256 + t] = f1;
  }
}

// ---------- per step: rt = [ftbI@WvI | ftbG@WvG]  M=256 N=1024 K=256 ----------
__global__ __launch_bounds__(256) void k_rt(
    const float* __restrict__ ftbI, const float* __restrict__ ftbG,
    const float* __restrict__ WvI,  const float* __restrict__ WvG,
    float* __restrict__ rt)
{
  int bx = blockIdx.x & 15, by = blockIdx.x >> 4;
  int n0 = bx * 64, m0 = by * 64;
  const float* Ap = (n0 < 512) ? ftbI : ftbG;
  const float* Bp = (n0 < 512) ? WvI  : WvG;
  int nb = (n0 < 512) ? n0 : n0 - 512;
  __shared__ float As[16][64];
  __shared__ float Bs[16][64];
  int tid = threadIdx.x, tx = tid & 15, ty = tid >> 4;
  float acc[4][4] = {};
  int am = tid >> 2, ak = (tid & 3) * 4;
  int bk = tid >> 4, bn = (tid & 15) * 4;
  const float* arow = Ap + (size_t)(m0 + am) * 256;
  for (int k0 = 0; k0 < 256; k0 += 16) {
    float4 av = *(const float4*)(arow + k0 + ak);
    As[ak+0][am] = av.x; As[ak+1][am] = av.y; As[ak+2][am] = av.z; As[ak+3][am] = av.w;
    *(float4*)&Bs[bk][bn] = *(const float4*)(Bp + (size_t)(k0 + bk) * 512 + nb + bn);
    __syncthreads();
    #pragma unroll
    for (int kk = 0; kk < 16; ++kk) {
      float a0 = As[kk][ty*4+0], a1 = As[kk][ty*4+1], a2 = As[kk][ty*4+2], a3 = As[kk][ty*4+3];
      float b0 = Bs[kk][tx*4+0], b1 = Bs[kk][tx*4+1], b2 = Bs[kk][tx*4+2], b3 = Bs[kk][tx*4+3];
      acc[0][0]=fmaf(a0,b0,acc[0][0]); acc[0][1]=fmaf(a0,b1,acc[0][1]); acc[0][2]=fmaf(a0,b2,acc[0][2]); acc[0][3]=fmaf(a0,b3,acc[0][3]);
      acc[1][0]=fmaf(a1,b0,acc[1][0]); acc[1][1]=fmaf(a1,b1,acc[1][1]); acc[1][2]=fmaf(a1,b2,acc[1][2]); acc[1][3]=fmaf(a1,b3,acc[1][3]);
      acc[2][0]=fmaf(a2,b0,acc[2][0]); acc[2][1]=fmaf(a2,b1,acc[2][1]); acc[2][2]=fmaf(a2,b2,acc[2][2]); acc[2][3]=fmaf(a2,b3,acc[2][3]);
      acc[3][0]=fmaf(a3,b0,acc[3][0]); acc[3][1]=fmaf(a3,b1,acc[3][1]); acc[3][2]=fmaf(a3,b2,acc[3][2]); acc[3][3]=fmaf(a3,b3,acc[3][3]);
    }
    __syncthreads();
  }
  #pragma unroll
  for (int i = 0; i < 4; ++i) {
    float4 v = make_float4(acc[i][0], acc[i][1], acc[i][2], acc[i][3]);
    *(float4*)(rt + (size_t)(m0 + ty*4 + i) * 1024 + n0 + tx*4) = v;
  }
}

// ---------- per step: defuzzify -> r ----------
__global__ __launch_bounds__(256) void k_defuzz(
    const float* __restrict__ rt,
    const float* __restrict__ a_p, const float* __restrict__ b_p,
    float* __restrict__ r_out)
{
  int b = blockIdx.x, t = threadIdx.x;
  float ab = fmaxf(a_p[0], 0.001f), bb = fmaxf(b_p[0], 0.001f);
  const float* rb = rt + (size_t)b * 1024;
  float rI = defuzz_one(rb[t],       rb[256 + t], ab, bb);
  float rG = defuzz_one(rb[512 + t], rb[768 + t], ab, bb);
  r_out[(size_t)b*256 + t] = 0.5f * rI + 0.5f * rG;
}

// ---------- per step: rW = r @ [W1 | Wf | Wi]  M=256 N=1024 K=256 ----------
__global__ __launch_bounds__(256) void k_rW(
    const float* __restrict__ r,
    const float* __restrict__ W1, const float* __restrict__ Wf, const float* __restrict__ Wi,
    float* __restrict__ rW1, float* __restrict__ rWf, float* __restrict__ rWi)
{
  int bx = blockIdx.x & 15, by = blockIdx.x >> 4;
  int n0 = bx * 64, m0 = by * 64;
  const float* Bp; int ldb, nb;
  if (n0 < 512)      { Bp = W1; ldb = 512; nb = n0; }
  else if (n0 < 768) { Bp = Wf; ldb = 256; nb = n0 - 512; }
  else               { Bp = Wi; ldb = 256; nb = n0 - 768; }
  __shared__ float As[16][64];
  __shared__ float Bs[16][64];
  int tid = threadIdx.x, tx = tid & 15, ty = tid >> 4;
  float acc[4][4] = {};
  int am = tid >> 2, ak = (tid & 3) * 4;
  int bk = tid >> 4, bn = (tid & 15) * 4;
  const float* arow = r + (size_t)(m0 + am) * 256;
  for (int k0 = 0; k0 < 256; k0 += 16) {
    float4 av = *(const float4*)(arow + k0 + ak);
    As[ak+0][am] = av.x; As[ak+1][am] = av.y; As[ak+2][am] = av.z; As[ak+3][am] = av.w;
    *(float4*)&Bs[bk][bn] = *(const float4*)(Bp + (size_t)(k0 + bk) * ldb + nb + bn);
    __syncthreads();
    #pragma unroll
    for (int kk = 0; kk < 16; ++kk) {
      float a0 = As[kk][ty*4+0], a1 = As[kk][ty*4+1], a2 = As[kk][ty*4+2], a3 = As[kk][ty*4+3];
      float b0 = Bs[kk][tx*4+0], b1 = Bs[kk][tx*4+1], b2 = Bs[kk][tx*4+2], b3 = Bs[kk][tx*4+3];
      acc[0][0]=fmaf(a0,b0,acc[0][0]); acc[0][1]=fmaf(a0,b1,acc[0][1]); acc[0][2]=fmaf(a0,b2,acc[0][2]); acc[0][3]=fmaf(a0,b3,acc[0][3]);
      acc[1][0]=fmaf(a1,b0,acc[1][0]); acc[1][1]=fmaf(a1,b1,acc[1][1]); acc[1][2]=fmaf(a1,b2,acc[1][2]); acc[1][3]=fmaf(a1,b3,acc[1][3]);
      acc[2][0]=fmaf(a2,b0,acc[2][0]); acc[2][1]=fmaf(a2,b1,acc[2][1]); acc[2][2]=fmaf(a2,b2,acc[2][2]); acc[2][3]=fmaf(a2,b3,acc[2][3]);
      acc[3][0]=fmaf(a3,b0,acc[3][0]); acc[3][1]=fmaf(a3,b1,acc[3][1]); acc[3][2]=fmaf(a3,b2,acc[3][2]); acc[3][3]=fmaf(a3,b3,acc[3][3]);
    }
    __syncthreads();
  }
  #pragma unroll
  for (int i = 0; i < 4; ++i) {
    int row = m0 + ty*4 + i;
    float4 v = make_float4(acc[i][0], acc[i][1], acc[i][2], acc[i][3]);
    int c = tx * 4;
    if (n0 < 512)      *(float4*)(rW1 + (size_t)row*512 + n0 + c)        = v;
    else if (n0 < 768) *(float4*)(rWf + (size_t)row*256 + (n0-512) + c)  = v;
    else               *(float4*)(rWi + (size_t)row*256 + (n0-768) + c)  = v;
  }
}

// ---------- per step: GEMM1 128x128 + FULL epilogue ----------
// bx<4: A2 = bf16(gelu(acc + rW1 + b1)); bx 4-5: Gf = bf16(sigmoid(rWf+bf+tanh(acc)));
// bx 6-7: Gi = bf16(sigmoid(rWi+bi+tanh(acc)))
__global__ __launch_bounds__(256) void mfma_gemm1(
    const unsigned short* __restrict__ Fb_all, int bcast,
    const unsigned short* __restrict__ B1t,
    const float* __restrict__ rW1, const float* __restrict__ b1,
    const float* __restrict__ rWf, const float* __restrict__ bfv,
    const float* __restrict__ rWi, const float* __restrict__ biv,
    unsigned short* __restrict__ A2, unsigned short* __restrict__ Gf, unsigned short* __restrict__ Gi)
{
  int bx = blockIdx.x & 7, by = blockIdx.x >> 3;
  int n0 = bx * 128, m0 = by * 128;
  __shared__ __align__(16) short As[128][72];
  __shared__ __align__(16) short Bs[128][72];
  int tid = threadIdx.x;
  int w = tid >> 6, wm = w >> 1, wn = w & 1, lane = tid & 63, lr = lane & 15, lh = lane >> 4;
  f32x4 acc[4][4] = {};
  int srow = tid >> 3, koff = (tid & 7) * 8;
  for (int k0 = 0; k0 < 256; k0 += 64) {
    #pragma unroll
    for (int rnd = 0; rnd < 4; ++rnd) {
      int rrow = rnd * 32 + srow;
      int ar = bcast ? ((m0 + rrow) & 63) : (m0 + rrow);
      *(float4*)&As[rrow][koff] = *(const float4*)&Fb_all[(size_t)ar * 256 + k0 + koff];
      *(float4*)&Bs[rrow][koff] = *(const float4*)&B1t[(size_t)(n0 + rrow) * 256 + k0 + koff];
    }
    __syncthreads();
    #pragma unroll
    for (int ks = 0; ks < 2; ++ks) {
      short8v a[4], b[4];
      #pragma unroll
      for (int m = 0; m < 4; ++m) a[m] = *(const short8v*)&As[wm*64 + m*16 + lr][ks*32 + lh*8];
      #pragma unroll
      for (int n = 0; n < 4; ++n) b[n] = *(const short8v*)&Bs[wn*64 + n*16 + lr][ks*32 + lh*8];
      #pragma unroll
      for (int m = 0; m < 4; ++m)
        #pragma unroll
        for (int n = 0; n < 4; ++n)
          acc[m][n] = __builtin_amdgcn_mfma_f32_16x16x32_bf16(a[m], b[n], acc[m][n], 0, 0, 0);
    }
    __syncthreads();
  }

  int b_ix = (m0 >> 6) + wm;
  if (bx < 4) {
    const float* rwp = rW1 + (size_t)b_ix * 512;
    #pragma unroll
    for (int n = 0; n < 4; ++n) {
      int col = n0 + wn*64 + n*16 + lr;
      float add = rwp[col] + b1[col];
      #pragma unroll
      for (int m = 0; m < 4; ++m) {
        int rbase = m0 + wm*64 + m*16 + lh*4;
        #pragma unroll
        for (int r = 0; r < 4; ++r)
          A2[(size_t)(rbase + r) * 512 + col] = f2bf(gelu_f(acc[m][n][r] + add));
      }
    }
  } else {
    int isI = (bx >= 6);
    const float* rwp = (isI ? rWi : rWf) + (size_t)b_ix * 256;
    const float* bp  = isI ? biv : bfv;
    unsigned short* outp = isI ? Gi : Gf;
    int cb = isI ? 768 : 512;
    #pragma unroll
    for (int n = 0; n < 4; ++n) {
      int c = n0 + wn*64 + n*16 + lr - cb;
      float add = rwp[c] + bp[c];
      #pragma unroll
      for (int m = 0; m < 4; ++m) {
        int rbase = m0 + wm*64 + m*16 + lh*4;
        #pragma unroll
        for (int r = 0; r < 4; ++r)
          outp[(size_t)(rbase + r) * 256 + c] = f2bf(sigmoid_f(add + tanh_fast(acc[m][n][r])));
      }
    }
  }
}

// ---------- per step: GEMM2 64x128 tiles, plain stage, gate epilogue ----------
__global__ __launch_bounds__(256) void mfma_gemm2(
    const unsigned short* __restrict__ A2, const unsigned short* __restrict__ W2t,
    const float* __restrict__ b2,
    const float* __restrict__ Fprev, const float* __restrict__ FT, int bcast,
    const float* __restrict__ rr,
    const unsigned short* __restrict__ Gf, const unsigned short* __restrict__ Gi,
    float* __restrict__ Fout, unsigned short* __restrict__ Fbf)
{
  int bx = blockIdx.x & 1, by = blockIdx.x >> 1;
  int n0 = bx * 128, m0 = by * 64;
  __shared__ __align__(16) short As[64][72];
  __shared__ __align__(16) short Bs[128][72];
  int tid = threadIdx.x;
  int w = tid >> 6, lane = tid & 63, lr = lane & 15, lh = lane >> 4;
  f32x4 acc[4][2] = {};
  int srow = tid >> 3, koff = (tid & 7) * 8;

  for (int k0 = 0; k0 < 512; k0 += 64) {
    #pragma unroll
    for (int rnd = 0; rnd < 2; ++rnd) {
      int rrow = rnd * 32 + srow;
      *(float4*)&As[rrow][koff] = *(const float4*)&A2[(size_t)(m0 + rrow) * 512 + k0 + koff];
    }
    #pragma unroll
    for (int rnd = 0; rnd < 4; ++rnd) {
      int rrow = rnd * 32 + srow;
      *(float4*)&Bs[rrow][koff] = *(const float4*)&W2t[(size_t)(n0 + rrow) * 512 + k0 + koff];
    }
    __syncthreads();
    #pragma unroll
    for (int ks = 0; ks < 2; ++ks) {
      short8v a[4], b[2];
      #pragma unroll
      for (int m = 0; m < 4; ++m) a[m] = *(const short8v*)&As[m*16 + lr][ks*32 + lh*8];
      #pragma unroll
      for (int n = 0; n < 2; ++n) b[n] = *(const short8v*)&Bs[w*32 + n*16 + lr][ks*32 + lh*8];
      #pragma unroll
      for (int m = 0; m < 4; ++m)
        #pragma unroll
        for (int n = 0; n < 2; ++n)
          acc[m][n] = __builtin_amdgcn_mfma_f32_16x16x32_bf16(a[m], b[n], acc[m][n], 0, 0, 0);
    }
    __syncthreads();
  }

  int bnum = by;
  const float* rp = rr + (size_t)bnum * 256;
  #pragma unroll
  for (int n = 0; n < 2; ++n) {
    int col = n0 + w*32 + n*16 + lr;
    float b2c = b2[col], rv = rp[col];
    #pragma unroll
    for (int m = 0; m < 4; ++m) {
      int rbase = m0 + m*16 + lh*4;
      #pragma unroll
      for (int r = 0; r < 4; ++r) {
        int row = rbase + r;
        float Ftv = bcast ? FT[(size_t)(row & 63) * 256 + col]
                          : Fprev[(size_t)row * 256 + col];
        float ftld = acc[m][n][r] + b2c + Ftv + rv;
        float fg = bfss(Gf[(size_t)row * 256 + col]);
        float ig = bfss(Gi[(size_t)row * 256 + col]);
        float ov = fg * Ftv + ig * tanh_fast(ftld);
        Fout[(size_t)row * 256 + col] = ov;
        Fbf[(size_t)row * 256 + col] = f2bf(ov);
      }
    }
  }
}

// ---------- host ----------
extern "C" void kernel_launch(void* const* d_in, const int* in_sizes, int n_in,
                              void* d_out, int out_size, void* d_ws, size_t ws_size,
                              hipStream_t stream)
{
  (void)in_sizes; (void)n_in; (void)out_size; (void)ws_size;
  const float* wsi  = (const float*)d_in[0];
  const float* gen  = (const float*)d_in[1];
  const float* FT   = (const float*)d_in[2];
  const float* W_lr = (const float*)d_in[3];
  const float* b_lr = (const float*)d_in[4];
  const float* W_g  = (const float*)d_in[5];
  const float* b_g  = (const float*)d_in[6];
  const float* WqI  = (const float*)d_in[7];
  const float* WqG  = (const float*)d_in[8];
  const float* WkI  = (const float*)d_in[9];
  const float* WkG  = (const float*)d_in[10];
  const float* WvI  = (const float*)d_in[11];
  const float* WvG  = (const float*)d_in[12];
  const float* W1   = (const float*)d_in[13];
  const float* b1   = (const float*)d_in[14];
  const float* W2   = (const float*)d_in[15];
  const float* b2   = (const float*)d_in[16];
  const float* Wf   = (const float*)d_in[17];
  const float* bf   = (const float*)d_in[18];
  const float* Wi   = (const float*)d_in[19];
  const float* bi   = (const float*)d_in[20];
  const float* Vf   = (const float*)d_in[21];
  const float* Vi   = (const float*)d_in[22];
  const float* a_p  = (const float*)d_in[23];
  const float* b_p  = (const float*)d_in[24];

  float* out = (float*)d_out;
  float* ws  = (float*)d_ws;
  // fp32 region
  float* rr    = ws;                    // 256*256
  float* rW1   = rr    + 65536;         // 256*512
  float* rWf   = rW1   + 131072;
  float* rWi   = rWf   + 65536;
  float* qIp   = rWi   + 65536;
  float* qGp   = qIp   + 65536;
  float* lrf   = qGp   + 65536;         // 256*512
  float* gf    = lrf   + 131072;
  float* QI    = gf    + 131072;
  float* QG    = QI    + 65536;
  float* WkIt  = QG    + 65536;
  float* WkGt  = WkIt  + 65536;
  float* ftbI  = WkGt  + 65536;         // 256*256
  float* ftbG  = ftbI  + 65536;
  float* rt    = ftbG  + 65536;         // 256*1024
  // bf16 region
  unsigned short* A2   = (unsigned short*)(rt + 262144);   // 16384*512
  unsigned short* Gfb  = A2   + 8388608;                   // 16384*256
  unsigned short* Gib  = Gfb  + 4194304;                   // 16384*256
  unsigned short* Fbf  = Gib  + 4194304;                   // 16384*256
  unsigned short* FTbf = Fbf  + 4194304;                   // 64*256
  unsigned short* B1t  = FTbf + 16384;                     // 1024*256
  unsigned short* W2t  = B1t  + 262144;                    // 256*512

  k_convert<<<2112, 256, 0, stream>>>(W1, Vf, Vi, W2, FT, WkI, WkG,
                                      B1t, W2t, FTbf, WkIt, WkGt);
  k_pre_lin<<<32, 256, 0, stream>>>(wsi, gen, W_lr, b_lr, W_g, b_g, a_p, b_p, lrf, gf);
  k_pre_q<<<32, 256, 0, stream>>>(lrf, gf, WqI, WqG, QI, QG);
  k_pre_qp<<<32, 256, 0, stream>>>(QI, QG, WkIt, WkGt, qIp, qGp);

  // out[j] = F_{8-j}; step st produces F_{st+1} -> slot 7-st.
  const float* Fcur = nullptr;
  int bcast = 1;
  for (int st = 0; st < T_; ++st) {
    float* Fnext = out + (size_t)(7 - st) * NROW * D_;
    k_ftbar<<<256, 256, 0, stream>>>(bcast ? FTbf : Fbf, bcast, qIp, qGp, ftbI, ftbG);
    k_rt<<<64, 256, 0, stream>>>(ftbI, ftbG, WvI, WvG, rt);
    k_defuzz<<<256, 256, 0, stream>>>(rt, a_p, b_p, rr);
    k_rW<<<64, 256, 0, stream>>>(rr, W1, Wf, Wi, rW1, rWf, rWi);
    mfma_gemm1<<<1024, 256, 0, stream>>>(bcast ? FTbf : Fbf, bcast, B1t,
                                         rW1, b1, rWf, bf, rWi, bi,
                                         A2, Gfb, Gib);
    mfma_gemm2<<<512, 256, 0, stream>>>(A2, W2t, b2, Fcur, FT, bcast, rr,
                                        Gfb, Gib, Fnext, Fbf);
    Fcur = Fnext;
    bcast = 0;
  }
}

// Round 10
// 972.320 us; speedup vs baseline: 1.2423x; 1.2423x over previous
//
#include <hip/hip_runtime.h>
#include <hip/hip_bf16.h>

// Problem constants
#define B_    256
#define K_    64
#define D_    256
#define T_    8
#define NROW  (B_*K_)

typedef short short8v __attribute__((ext_vector_type(8)));
typedef float f32x4  __attribute__((ext_vector_type(4)));

// ---------- device helpers ----------
__device__ __forceinline__ float fexp2(float x) { return __builtin_amdgcn_exp2f(x); }
__device__ __forceinline__ float flog2(float x) { return __builtin_amdgcn_logf(x); }

__device__ __forceinline__ float sigmoid_f(float x) {
  return 1.f / (1.f + fexp2(x * -1.4426950408889634f));
}
__device__ __forceinline__ float tanh_fast(float x) {
  float xc = fminf(fmaxf(x, -30.f), 30.f);
  float t = fexp2(xc * 2.8853900817779268f);   // e^(2x)
  return (t - 1.f) / (t + 1.f);
}
__device__ __forceinline__ float gelu_f(float x) {
  return 0.5f * x * (1.f + erff(x * 0.70710678118654752440f));
}
__device__ __forceinline__ unsigned short f2bf(float x) {
  __hip_bfloat16 h = __float2bfloat16(x);
  return *reinterpret_cast<unsigned short*>(&h);
}
__device__ __forceinline__ float bfss(unsigned short s) {
  return __uint_as_float(((unsigned int)s) << 16);
}
__device__ __forceinline__ float muS_f(float x, float a2, float b2) {
  float mid = 0.5f * (a2 + b2);
  float inv = 1.f / (b2 - a2 + 1e-12f);
  if (x > b2)  return 1.f;
  if (x > mid) { float u = (b2 - x) * inv; return 1.f - 2.f * u * u; }
  if (x > a2)  { float u = (x - a2) * inv; return 2.f * u * u; }
  return 0.f;
}
__device__ __forceinline__ float pow_abs(float z, float e2b) {
  return fexp2(e2b * flog2(fabsf(z)));
}
__device__ __forceinline__ float defuzz_one(float rb_, float rs_, float ab, float bb) {
  float e2b = 2.f * bb;
  float inv_ab = 1.f / ab;
  float cb = 4.f * tanh_fast(rb_);
  float num = 0.f, den = 0.f;
  #pragma unroll
  for (int j = 0; j < 41; ++j) {
    float gj = -4.f + 0.2f * (float)j;
    float mu = 1.f / (1.f + pow_abs((gj - cb) * inv_ab, e2b));
    num += gj * mu; den += mu;
  }
  float cenb = num / (den + 1e-12f);
  float cs = 4.f * tanh_fast(rs_);
  float as_ = fminf(fmaxf(cs - 1.f, -4.f), 4.f);
  float bs_ = fminf(fmaxf(cs + 1.f, -4.f), 4.f);
  num = 0.f; den = 0.f;
  {
    float mid = 0.5f * (as_ + bs_);
    float inv = 1.f / (bs_ - as_ + 1e-12f);
    #pragma unroll
    for (int j = 0; j < 41; ++j) {
      float gj = -4.f + 0.2f * (float)j;
      float mu;
      if (gj > bs_)      mu = 1.f;
      else if (gj > mid) { float u = (bs_ - gj) * inv; mu = 1.f - 2.f * u * u; }
      else if (gj > as_) { float u = (gj - as_) * inv; mu = 2.f * u * u; }
      else               mu = 0.f;
      num += gj * mu; den += mu;
    }
  }
  float cens = num / (den + 1e-12f);
  return 0.5f * cenb + 0.5f * cens;
}

// ---------- one-time: weight transposes / bf16 conversions ----------
__global__ __launch_bounds__(256) void k_convert(
    const float* __restrict__ W1, const float* __restrict__ Vf, const float* __restrict__ Vi,
    const float* __restrict__ W2, const float* __restrict__ FT,
    const float* __restrict__ WkI, const float* __restrict__ WkG,
    unsigned short* __restrict__ B1t, unsigned short* __restrict__ W2t,
    unsigned short* __restrict__ FTbf,
    float* __restrict__ WkIt, float* __restrict__ WkGt)
{
  int idx = blockIdx.x * 256 + threadIdx.x;
  if (idx < 262144) {
    int n = idx >> 8, k = idx & 255;
    float v = (n < 512) ? W1[(size_t)k*512 + n]
            : (n < 768) ? Vf[(size_t)k*256 + (n-512)]
                        : Vi[(size_t)k*256 + (n-768)];
    B1t[idx] = f2bf(v);
  } else if (idx < 393216) {
    int j = idx - 262144;
    int n = j >> 9, k = j & 511;
    W2t[j] = f2bf(W2[(size_t)k*256 + n]);
  } else if (idx < 409600) {
    int j = idx - 393216;
    FTbf[j] = f2bf(FT[j]);
  } else if (idx < 475136) {
    int j = idx - 409600;
    int k = j >> 8, n = j & 255;
    WkIt[j] = WkI[(size_t)n*256 + k];
  } else if (idx < 540672) {
    int j = idx - 475136;
    int k = j >> 8, n = j & 255;
    WkGt[j] = WkG[(size_t)n*256 + k];
  }
}

// ---------- precompute stage 1: lr/g linear + fuzzify ----------
__global__ __launch_bounds__(256) void k_pre_lin(
    const float* __restrict__ wsi, const float* __restrict__ gen,
    const float* __restrict__ W_lr, const float* __restrict__ b_lr,
    const float* __restrict__ W_g,  const float* __restrict__ b_g,
    const float* __restrict__ a_p,  const float* __restrict__ b_p,
    float* __restrict__ lrf, float* __restrict__ gf)
{
  int g_ix = blockIdx.x;
  int half = g_ix >> 4, tile = g_ix & 15;
  int bx = tile & 3, by = tile >> 2;
  int n0 = bx * 64, m0 = by * 64;
  const float* A    = half ? gen  : wsi;
  const float* Bm   = half ? W_g  : W_lr;
  const float* bias = half ? b_g  : b_lr;
  float* outp       = half ? gf   : lrf;
  int KK            = half ? 512  : 1024;
  float ab = fmaxf(a_p[0], 0.001f), bb = fmaxf(b_p[0], 0.001f);
  float e2b = 2.f * bb, inv_ab = 1.f / ab;

  __shared__ float As[16][64];
  __shared__ float Bs[16][64];
  int tid = threadIdx.x, tx = tid & 15, ty = tid >> 4;
  float acc[4][4] = {};
  int am = tid >> 2, ak = (tid & 3) * 4;
  int bk = tid >> 4, bn = (tid & 15) * 4;
  const float* arow = A + (size_t)(m0 + am) * KK;
  for (int k0 = 0; k0 < KK; k0 += 16) {
    float4 av = *(const float4*)(arow + k0 + ak);
    As[ak+0][am] = av.x; As[ak+1][am] = av.y; As[ak+2][am] = av.z; As[ak+3][am] = av.w;
    *(float4*)&Bs[bk][bn] = *(const float4*)(Bm + (size_t)(k0 + bk) * 256 + n0 + bn);
    __syncthreads();
    #pragma unroll
    for (int kk = 0; kk < 16; ++kk) {
      float a0 = As[kk][ty*4+0], a1 = As[kk][ty*4+1], a2 = As[kk][ty*4+2], a3 = As[kk][ty*4+3];
      float b0 = Bs[kk][tx*4+0], b1 = Bs[kk][tx*4+1], b2 = Bs[kk][tx*4+2], b3 = Bs[kk][tx*4+3];
      acc[0][0]=fmaf(a0,b0,acc[0][0]); acc[0][1]=fmaf(a0,b1,acc[0][1]); acc[0][2]=fmaf(a0,b2,acc[0][2]); acc[0][3]=fmaf(a0,b3,acc[0][3]);
      acc[1][0]=fmaf(a1,b0,acc[1][0]); acc[1][1]=fmaf(a1,b1,acc[1][1]); acc[1][2]=fmaf(a1,b2,acc[1][2]); acc[1][3]=fmaf(a1,b3,acc[1][3]);
      acc[2][0]=fmaf(a2,b0,acc[2][0]); acc[2][1]=fmaf(a2,b1,acc[2][1]); acc[2][2]=fmaf(a2,b2,acc[2][2]); acc[2][3]=fmaf(a2,b3,acc[2][3]);
      acc[3][0]=fmaf(a3,b0,acc[3][0]); acc[3][1]=fmaf(a3,b1,acc[3][1]); acc[3][2]=fmaf(a3,b2,acc[3][2]); acc[3][3]=fmaf(a3,b3,acc[3][3]);
    }
    __syncthreads();
  }
  #pragma unroll
  for (int i = 0; i < 4; ++i) {
    int row = m0 + ty*4 + i;
    #pragma unroll
    for (int j = 0; j < 4; ++j) {
      int col = n0 + tx*4 + j;
      float v = acc[i][j] + bias[col];
      float xs = 4.f * tanh_fast(v * 0.25f);
      outp[(size_t)row*512 + col]       = 1.f / (1.f + pow_abs(xs * inv_ab, e2b));
      outp[(size_t)row*512 + col + 256] = muS_f(xs, -1.f, 1.f);
    }
  }
}

// ---------- precompute stage 2: QI = lrf@WqI, QG = gf@WqG ----------
__global__ __launch_bounds__(256) void k_pre_q(
    const float* __restrict__ lrf, const float* __restrict__ gf,
    const float* __restrict__ WqI, const float* __restrict__ WqG,
    float* __restrict__ QI, float* __restrict__ QG)
{
  int g_ix = blockIdx.x;
  int half = g_ix >> 4, tile = g_ix & 15;
  int bx = tile & 3, by = tile >> 2;
  int n0 = bx * 64, m0 = by * 64;
  const float* A  = half ? gf  : lrf;
  const float* Bm = half ? WqG : WqI;
  float* outp     = half ? QG  : QI;

  __shared__ float As[16][64];
  __shared__ float Bs[16][64];
  int tid = threadIdx.x, tx = tid & 15, ty = tid >> 4;
  float acc[4][4] = {};
  int am = tid >> 2, ak = (tid & 3) * 4;
  int bk = tid >> 4, bn = (tid & 15) * 4;
  const float* arow = A + (size_t)(m0 + am) * 512;
  for (int k0 = 0; k0 < 512; k0 += 16) {
    float4 av = *(const float4*)(arow + k0 + ak);
    As[ak+0][am] = av.x; As[ak+1][am] = av.y; As[ak+2][am] = av.z; As[ak+3][am] = av.w;
    *(float4*)&Bs[bk][bn] = *(const float4*)(Bm + (size_t)(k0 + bk) * 256 + n0 + bn);
    __syncthreads();
    #pragma unroll
    for (int kk = 0; kk < 16; ++kk) {
      float a0 = As[kk][ty*4+0], a1 = As[kk][ty*4+1], a2 = As[kk][ty*4+2], a3 = As[kk][ty*4+3];
      float b0 = Bs[kk][tx*4+0], b1 = Bs[kk][tx*4+1], b2 = Bs[kk][tx*4+2], b3 = Bs[kk][tx*4+3];
      acc[0][0]=fmaf(a0,b0,acc[0][0]); acc[0][1]=fmaf(a0,b1,acc[0][1]); acc[0][2]=fmaf(a0,b2,acc[0][2]); acc[0][3]=fmaf(a0,b3,acc[0][3]);
      acc[1][0]=fmaf(a1,b0,acc[1][0]); acc[1][1]=fmaf(a1,b1,acc[1][1]); acc[1][2]=fmaf(a1,b2,acc[1][2]); acc[1][3]=fmaf(a1,b3,acc[1][3]);
      acc[2][0]=fmaf(a2,b0,acc[2][0]); acc[2][1]=fmaf(a2,b1,acc[2][1]); acc[2][2]=fmaf(a2,b2,acc[2][2]); acc[2][3]=fmaf(a2,b3,acc[2][3]);
      acc[3][0]=fmaf(a3,b0,acc[3][0]); acc[3][1]=fmaf(a3,b1,acc[3][1]); acc[3][2]=fmaf(a3,b2,acc[3][2]); acc[3][3]=fmaf(a3,b3,acc[3][3]);
    }
    __syncthreads();
  }
  #pragma unroll
  for (int i = 0; i < 4; ++i) {
    float4 v = make_float4(acc[i][0], acc[i][1], acc[i][2], acc[i][3]);
    *(float4*)(outp + (size_t)(m0 + ty*4 + i) * 256 + n0 + tx*4) = v;
  }
}

// ---------- precompute stage 3: qIp = QI@WkIt, qGp = QG@WkGt ----------
__global__ __launch_bounds__(256) void k_pre_qp(
    const float* __restrict__ QI, const float* __restrict__ QG,
    const float* __restrict__ WkIt, const float* __restrict__ WkGt,
    float* __restrict__ qIp, float* __restrict__ qGp)
{
  int g_ix = blockIdx.x;
  int half = g_ix >> 4, tile = g_ix & 15;
  int bx = tile & 3, by = tile >> 2;
  int n0 = bx * 64, m0 = by * 64;
  const float* A  = half ? QG   : QI;
  const float* Bm = half ? WkGt : WkIt;
  float* outp     = half ? qGp  : qIp;

  __shared__ float As[16][64];
  __shared__ float Bs[16][64];
  int tid = threadIdx.x, tx = tid & 15, ty = tid >> 4;
  float acc[4][4] = {};
  int am = tid >> 2, ak = (tid & 3) * 4;
  int bk = tid >> 4, bn = (tid & 15) * 4;
  const float* arow = A + (size_t)(m0 + am) * 256;
  for (int k0 = 0; k0 < 256; k0 += 16) {
    float4 av = *(const float4*)(arow + k0 + ak);
    As[ak+0][am] = av.x; As[ak+1][am] = av.y; As[ak+2][am] = av.z; As[ak+3][am] = av.w;
    *(float4*)&Bs[bk][bn] = *(const float4*)(Bm + (size_t)(k0 + bk) * 256 + n0 + bn);
    __syncthreads();
    #pragma unroll
    for (int kk = 0; kk < 16; ++kk) {
      float a0 = As[kk][ty*4+0], a1 = As[kk][ty*4+1], a2 = As[kk][ty*4+2], a3 = As[kk][ty*4+3];
      float b0 = Bs[kk][tx*4+0], b1 = Bs[kk][tx*4+1], b2 = Bs[kk][tx*4+2], b3 = Bs[kk][tx*4+3];
      acc[0][0]=fmaf(a0,b0,acc[0][0]); acc[0][1]=fmaf(a0,b1,acc[0][1]); acc[0][2]=fmaf(a0,b2,acc[0][2]); acc[0][3]=fmaf(a0,b3,acc[0][3]);
      acc[1][0]=fmaf(a1,b0,acc[1][0]); acc[1][1]=fmaf(a1,b1,acc[1][1]); acc[1][2]=fmaf(a1,b2,acc[1][2]); acc[1][3]=fmaf(a1,b3,acc[1][3]);
      acc[2][0]=fmaf(a2,b0,acc[2][0]); acc[2][1]=fmaf(a2,b1,acc[2][1]); acc[2][2]=fmaf(a2,b2,acc[2][2]); acc[2][3]=fmaf(a2,b3,acc[2][3]);
      acc[3][0]=fmaf(a3,b0,acc[3][0]); acc[3][1]=fmaf(a3,b1,acc[3][1]); acc[3][2]=fmaf(a3,b2,acc[3][2]); acc[3][3]=fmaf(a3,b3,acc[3][3]);
    }
    __syncthreads();
  }
  #pragma unroll
  for (int i = 0; i < 4; ++i) {
    float4 v = make_float4(acc[i][0], acc[i][1], acc[i][2], acc[i][3]);
    *(float4*)(outp + (size_t)(m0 + ty*4 + i) * 256 + n0 + tx*4) = v;
  }
}

// ---------- per step: ftbar (scores+softmax+weighted-sum), one block per batch ----------
__global__ __launch_bounds__(256) void k_ftbar(
    const unsigned short* __restrict__ Fb_all, int bcast,
    const float* __restrict__ qIp, const float* __restrict__ qGp,
    float* __restrict__ ftbI, float* __restrict__ ftbG)
{
  __shared__ __align__(16) char smem[38912];
  int b = blockIdx.x, t = threadIdx.x;
  short* Fs  = (short*)smem;                  // [64][264] bf16
  float* qv  = (float*)(smem + 33792);        // [512]
  float* red = (float*)(smem + 35840);        // [512]
  float* prl = (float*)(smem + 37888);        // p [128]

  const unsigned short* Fsrc = bcast ? Fb_all : (Fb_all + (size_t)b * K_ * D_);
  #pragma unroll
  for (int i = 0; i < 8; ++i) {
    int sidx = (i * 256 + t) * 8;
    int row = sidx >> 8, col = sidx & 255;
    *(float4*)&Fs[row * 264 + col] = *(const float4*)&Fsrc[sidx];
  }
  qv[t]       = qIp[(size_t)b*256 + t];
  qv[256 + t] = qGp[(size_t)b*256 + t];
  __syncthreads();
  {
    int k = t & 63, part = t >> 6;
    const unsigned int* frow = (const unsigned int*)&Fs[k * 264 + part * 64];
    const float* q0 = qv + part * 64;
    const float* q1 = qv + 256 + part * 64;
    float s0 = 0.f, s1 = 0.f;
    #pragma unroll
    for (int d2 = 0; d2 < 32; ++d2) {
      unsigned int pr = frow[d2];
      float f0 = __uint_as_float(pr << 16);
      float f1 = __uint_as_float(pr & 0xffff0000u);
      s0 = fmaf(f1, q0[2*d2+1], fmaf(f0, q0[2*d2], s0));
      s1 = fmaf(f1, q1[2*d2+1], fmaf(f0, q1[2*d2], s1));
    }
    red[t] = s0; red[256 + t] = s1;
  }
  __syncthreads();
  if (t < 128) {
    int which = t >> 6, kk = t & 63;
    const float* rp = red + which * 256;
    float s = (rp[kk] + rp[64+kk] + rp[128+kk] + rp[192+kk]) * (1.f/16.f);
    float m = s;
    for (int off = 32; off; off >>= 1) m = fmaxf(m, __shfl_xor(m, off, 64));
    float e = fexp2((s - m) * 1.4426950408889634f);
    float sum = e;
    for (int off = 32; off; off >>= 1) sum += __shfl_xor(sum, off, 64);
    prl[which * 64 + kk] = e / sum;
  }
  __syncthreads();
  {
    float f0 = 0.f, f1 = 0.f;
    #pragma unroll 8
    for (int kk = 0; kk < 64; ++kk) {
      float fv = bfss((unsigned short)Fs[kk * 264 + t]);
      f0 = fmaf(prl[kk],      fv, f0);
      f1 = fmaf(prl[64 + kk], fv, f1);
    }
    ftbI[(size_t)b*256 + t] = f0;
    ftbG[(size_t)b*256 + t] = f1;
  }
}

// ---------- per step: rt = [ftbI@WvI | ftbG@WvG]  M=256 N=1024 K=256 ----------
__global__ __launch_bounds__(256) void k_rt(
    const float* __restrict__ ftbI, const float* __restrict__ ftbG,
    const float* __restrict__ WvI,  const float* __restrict__ WvG,
    float* __restrict__ rt)
{
  int bx = blockIdx.x & 15, by = blockIdx.x >> 4;
  int n0 = bx * 64, m0 = by * 64;
  const float* Ap = (n0 < 512) ? ftbI : ftbG;
  const float* Bp = (n0 < 512) ? WvI  : WvG;
  int nb = (n0 < 512) ? n0 : n0 - 512;
  __shared__ float As[16][64];
  __shared__ float Bs[16][64];
  int tid = threadIdx.x, tx = tid & 15, ty = tid >> 4;
  float acc[4][4] = {};
  int am = tid >> 2, ak = (tid & 3) * 4;
  int bk = tid >> 4, bn = (tid & 15) * 4;
  const float* arow = Ap + (size_t)(m0 + am) * 256;
  for (int k0 = 0; k0 < 256; k0 += 16) {
    float4 av = *(const float4*)(arow + k0 + ak);
    As[ak+0][am] = av.x; As[ak+1][am] = av.y; As[ak+2][am] = av.z; As[ak+3][am] = av.w;
    *(float4*)&Bs[bk][bn] = *(const float4*)(Bp + (size_t)(k0 + bk) * 512 + nb + bn);
    __syncthreads();
    #pragma unroll
    for (int kk = 0; kk < 16; ++kk) {
      float a0 = As[kk][ty*4+0], a1 = As[kk][ty*4+1], a2 = As[kk][ty*4+2], a3 = As[kk][ty*4+3];
      float b0 = Bs[kk][tx*4+0], b1 = Bs[kk][tx*4+1], b2 = Bs[kk][tx*4+2], b3 = Bs[kk][tx*4+3];
      acc[0][0]=fmaf(a0,b0,acc[0][0]); acc[0][1]=fmaf(a0,b1,acc[0][1]); acc[0][2]=fmaf(a0,b2,acc[0][2]); acc[0][3]=fmaf(a0,b3,acc[0][3]);
      acc[1][0]=fmaf(a1,b0,acc[1][0]); acc[1][1]=fmaf(a1,b1,acc[1][1]); acc[1][2]=fmaf(a1,b2,acc[1][2]); acc[1][3]=fmaf(a1,b3,acc[1][3]);
      acc[2][0]=fmaf(a2,b0,acc[2][0]); acc[2][1]=fmaf(a2,b1,acc[2][1]); acc[2][2]=fmaf(a2,b2,acc[2][2]); acc[2][3]=fmaf(a2,b3,acc[2][3]);
      acc[3][0]=fmaf(a3,b0,acc[3][0]); acc[3][1]=fmaf(a3,b1,acc[3][1]); acc[3][2]=fmaf(a3,b2,acc[3][2]); acc[3][3]=fmaf(a3,b3,acc[3][3]);
    }
    __syncthreads();
  }
  #pragma unroll
  for (int i = 0; i < 4; ++i) {
    float4 v = make_float4(acc[i][0], acc[i][1], acc[i][2], acc[i][3]);
    *(float4*)(rt + (size_t)(m0 + ty*4 + i) * 1024 + n0 + tx*4) = v;
  }
}

// ---------- per step: defuzzify -> r ----------
__global__ __launch_bounds__(256) void k_defuzz(
    const float* __restrict__ rt,
    const float* __restrict__ a_p, const float* __restrict__ b_p,
    float* __restrict__ r_out)
{
  int b = blockIdx.x, t = threadIdx.x;
  float ab = fmaxf(a_p[0], 0.001f), bb = fmaxf(b_p[0], 0.001f);
  const float* rb = rt + (size_t)b * 1024;
  float rI = defuzz_one(rb[t],       rb[256 + t], ab, bb);
  float rG = defuzz_one(rb[512 + t], rb[768 + t], ab, bb);
  r_out[(size_t)b*256 + t] = 0.5f * rI + 0.5f * rG;
}

// ---------- per step: rW = r @ [W1 | Wf | Wi]  M=256 N=1024 K=256 ----------
__global__ __launch_bounds__(256) void k_rW(
    const float* __restrict__ r,
    const float* __restrict__ W1, const float* __restrict__ Wf, const float* __restrict__ Wi,
    float* __restrict__ rW1, float* __restrict__ rWf, float* __restrict__ rWi)
{
  int bx = blockIdx.x & 15, by = blockIdx.x >> 4;
  int n0 = bx * 64, m0 = by * 64;
  const float* Bp; int ldb, nb;
  if (n0 < 512)      { Bp = W1; ldb = 512; nb = n0; }
  else if (n0 < 768) { Bp = Wf; ldb = 256; nb = n0 - 512; }
  else               { Bp = Wi; ldb = 256; nb = n0 - 768; }
  __shared__ float As[16][64];
  __shared__ float Bs[16][64];
  int tid = threadIdx.x, tx = tid & 15, ty = tid >> 4;
  float acc[4][4] = {};
  int am = tid >> 2, ak = (tid & 3) * 4;
  int bk = tid >> 4, bn = (tid & 15) * 4;
  const float* arow = r + (size_t)(m0 + am) * 256;
  for (int k0 = 0; k0 < 256; k0 += 16) {
    float4 av = *(const float4*)(arow + k0 + ak);
    As[ak+0][am] = av.x; As[ak+1][am] = av.y; As[ak+2][am] = av.z; As[ak+3][am] = av.w;
    *(float4*)&Bs[bk][bn] = *(const float4*)(Bp + (size_t)(k0 + bk) * ldb + nb + bn);
    __syncthreads();
    #pragma unroll
    for (int kk = 0; kk < 16; ++kk) {
      float a0 = As[kk][ty*4+0], a1 = As[kk][ty*4+1], a2 = As[kk][ty*4+2], a3 = As[kk][ty*4+3];
      float b0 = Bs[kk][tx*4+0], b1 = Bs[kk][tx*4+1], b2 = Bs[kk][tx*4+2], b3 = Bs[kk][tx*4+3];
      acc[0][0]=fmaf(a0,b0,acc[0][0]); acc[0][1]=fmaf(a0,b1,acc[0][1]); acc[0][2]=fmaf(a0,b2,acc[0][2]); acc[0][3]=fmaf(a0,b3,acc[0][3]);
      acc[1][0]=fmaf(a1,b0,acc[1][0]); acc[1][1]=fmaf(a1,b1,acc[1][1]); acc[1][2]=fmaf(a1,b2,acc[1][2]); acc[1][3]=fmaf(a1,b3,acc[1][3]);
      acc[2][0]=fmaf(a2,b0,acc[2][0]); acc[2][1]=fmaf(a2,b1,acc[2][1]); acc[2][2]=fmaf(a2,b2,acc[2][2]); acc[2][3]=fmaf(a2,b3,acc[2][3]);
      acc[3][0]=fmaf(a3,b0,acc[3][0]); acc[3][1]=fmaf(a3,b1,acc[3][1]); acc[3][2]=fmaf(a3,b2,acc[3][2]); acc[3][3]=fmaf(a3,b3,acc[3][3]);
    }
    __syncthreads();
  }
  #pragma unroll
  for (int i = 0; i < 4; ++i) {
    int row = m0 + ty*4 + i;
    float4 v = make_float4(acc[i][0], acc[i][1], acc[i][2], acc[i][3]);
    int c = tx * 4;
    if (n0 < 512)      *(float4*)(rW1 + (size_t)row*512 + n0 + c)        = v;
    else if (n0 < 768) *(float4*)(rWf + (size_t)row*256 + (n0-512) + c)  = v;
    else               *(float4*)(rWi + (size_t)row*256 + (n0-768) + c)  = v;
  }
}

// ---------- per step: GEMM1 persistent-row (block = one batch, 64 rows) ----------
// A-fragments live in registers across all 16 column chunks; B chunks double-buffered.
__global__ __launch_bounds__(512) void k_g1(
    const unsigned short* __restrict__ Fb_all, int bcast,
    const unsigned short* __restrict__ B1t,
    const float* __restrict__ rW1, const float* __restrict__ b1,
    const float* __restrict__ rWf, const float* __restrict__ bfv,
    const float* __restrict__ rWi, const float* __restrict__ biv,
    unsigned short* __restrict__ A2, unsigned short* __restrict__ Gf, unsigned short* __restrict__ Gi)
{
  __shared__ __align__(16) short Fs[64*264];      // 33792 B
  __shared__ __align__(16) short Bst[2][64*264];  // 67584 B
  int b = blockIdx.x, tid = threadIdx.x;
  int w = tid >> 6, lane = tid & 63, lr = lane & 15, lh = lane >> 4;
  int wm = w >> 2, wn = w & 3;                    // wave tile: 32 rows x 16 cols

  const unsigned short* Fsrc = bcast ? Fb_all : (Fb_all + (size_t)b * 64 * 256);
  #pragma unroll
  for (int p = 0; p < 8; ++p) {
    int idx = (p*512 + tid) * 8;
    int row = idx >> 8, col = idx & 255;
    *(float4*)&Fs[row*264 + col] = *(const float4*)&Fsrc[idx];
  }
  #pragma unroll
  for (int p = 0; p < 8; ++p) {
    int idx = (p*512 + tid) * 8;
    int row = idx >> 8, col = idx & 255;
    *(float4*)&Bst[0][row*264 + col] = *(const float4*)&B1t[idx];
  }
  __syncthreads();

  // A fragments once: rows wm*32 + fr*16 + lr, k = ks*32 + lh*8
  short8v afr0[8], afr1[8];
  #pragma unroll
  for (int ks = 0; ks < 8; ++ks) {
    afr0[ks] = *(const short8v*)&Fs[(wm*32 + lr)*264      + ks*32 + lh*8];
    afr1[ks] = *(const short8v*)&Fs[(wm*32 + 16 + lr)*264 + ks*32 + lh*8];
  }

  for (int c = 0; c < 16; ++c) {
    float4 pf[8];
    if (c < 15) {
      const unsigned short* src = B1t + (size_t)(c+1) * 64 * 256;
      #pragma unroll
      for (int p = 0; p < 8; ++p) pf[p] = *(const float4*)&src[(p*512 + tid)*8];
    }
    f32x4 acc0 = {0.f,0.f,0.f,0.f}, acc1 = {0.f,0.f,0.f,0.f};
    const short* Bb = Bst[c & 1];
    #pragma unroll
    for (int ks = 0; ks < 8; ++ks) {
      short8v bf_ = *(const short8v*)&Bb[(wn*16 + lr)*264 + ks*32 + lh*8];
      acc0 = __builtin_amdgcn_mfma_f32_16x16x32_bf16(afr0[ks], bf_, acc0, 0, 0, 0);
      acc1 = __builtin_amdgcn_mfma_f32_16x16x32_bf16(afr1[ks], bf_, acc1, 0, 0, 0);
    }
    // epilogue: cols c*64 + wn*16 + lr (wave-uniform branch: 16-col span)
    int col = c*64 + wn*16 + lr;
    if (col < 512) {
      float add = rW1[(size_t)b*512 + col] + b1[col];
      #pragma unroll
      for (int r = 0; r < 4; ++r) {
        int row0 = b*64 + wm*32 + lh*4 + r;
        A2[(size_t)row0*512 + col]      = f2bf(gelu_f(acc0[r] + add));
        A2[(size_t)(row0+16)*512 + col] = f2bf(gelu_f(acc1[r] + add));
      }
    } else if (col < 768) {
      int cc = col - 512;
      float add = rWf[(size_t)b*256 + cc] + bfv[cc];
      #pragma unroll
      for (int r = 0; r < 4; ++r) {
        int row0 = b*64 + wm*32 + lh*4 + r;
        Gf[(size_t)row0*256 + cc]      = f2bf(sigmoid_f(add + tanh_fast(acc0[r])));
        Gf[(size_t)(row0+16)*256 + cc] = f2bf(sigmoid_f(add + tanh_fast(acc1[r])));
      }
    } else {
      int cc = col - 768;
      float add = rWi[(size_t)b*256 + cc] + biv[cc];
      #pragma unroll
      for (int r = 0; r < 4; ++r) {
        int row0 = b*64 + wm*32 + lh*4 + r;
        Gi[(size_t)row0*256 + cc]      = f2bf(sigmoid_f(add + tanh_fast(acc0[r])));
        Gi[(size_t)(row0+16)*256 + cc] = f2bf(sigmoid_f(add + tanh_fast(acc1[r])));
      }
    }
    if (c < 15) {
      short* Bn = Bst[(c+1) & 1];
      #pragma unroll
      for (int p = 0; p < 8; ++p) {
        int idx = (p*512 + tid) * 8;
        int row = idx >> 8, colk = idx & 255;
        *(float4*)&Bn[row*264 + colk] = pf[p];
      }
      __syncthreads();
    }
  }
}

// ---------- per step: GEMM2 persistent-row (block = one batch, 64 rows) ----------
// A2 fragments in registers across all 8 column chunks; W2t chunks double-buffered.
__global__ __launch_bounds__(512) void k_g2(
    const unsigned short* __restrict__ A2, const unsigned short* __restrict__ W2t,
    const float* __restrict__ b2,
    const float* __restrict__ Fprev, const float* __restrict__ FT, int bcast,
    const float* __restrict__ rr,
    const unsigned short* __restrict__ Gf, const unsigned short* __restrict__ Gi,
    float* __restrict__ Fout, unsigned short* __restrict__ Fbf)
{
  __shared__ __align__(16) short As2[64*520];     // 66560 B
  __shared__ __align__(16) short Wst[2][32*520];  // 66560 B
  int b = blockIdx.x, tid = threadIdx.x;
  int w = tid >> 6, lane = tid & 63, lr = lane & 15, lh = lane >> 4;
  int wm = w >> 1, wn = w & 1;                    // wave tile: 16 rows x 16 cols

  const unsigned short* Asrc = A2 + (size_t)b * 64 * 512;
  #pragma unroll
  for (int p = 0; p < 8; ++p) {
    int idx = (p*512 + tid) * 8;
    int row = idx >> 9, col = idx & 511;
    *(float4*)&As2[row*520 + col] = *(const float4*)&Asrc[idx];
  }
  #pragma unroll
  for (int p = 0; p < 4; ++p) {
    int idx = (p*512 + tid) * 8;
    int row = idx >> 9, col = idx & 511;
    *(float4*)&Wst[0][row*520 + col] = *(const float4*)&W2t[idx];
  }
  __syncthreads();

  short8v afr[16];
  #pragma unroll
  for (int ks = 0; ks < 16; ++ks)
    afr[ks] = *(const short8v*)&As2[(wm*16 + lr)*520 + ks*32 + lh*8];

  for (int c = 0; c < 8; ++c) {
    float4 pf[4];
    if (c < 7) {
      const unsigned short* src = W2t + (size_t)(c+1) * 32 * 512;
      #pragma unroll
      for (int p = 0; p < 4; ++p) pf[p] = *(const float4*)&src[(p*512 + tid)*8];
    }
    f32x4 acc = {0.f,0.f,0.f,0.f};
    const short* Wb = Wst[c & 1];
    #pragma unroll
    for (int ks = 0; ks < 16; ++ks) {
      short8v bf_ = *(const short8v*)&Wb[(wn*16 + lr)*520 + ks*32 + lh*8];
      acc = __builtin_amdgcn_mfma_f32_16x16x32_bf16(afr[ks], bf_, acc, 0, 0, 0);
    }
    int col = c*32 + wn*16 + lr;
    float b2c = b2[col], rv = rr[(size_t)b*256 + col];
    #pragma unroll
    for (int r = 0; r < 4; ++r) {
      int row = b*64 + wm*16 + lh*4 + r;
      float Ftv = bcast ? FT[(size_t)(row & 63)*256 + col]
                        : Fprev[(size_t)row*256 + col];
      float ftld = acc[r] + b2c + Ftv + rv;
      float fg = bfss(Gf[(size_t)row*256 + col]);
      float ig = bfss(Gi[(size_t)row*256 + col]);
      float ov = fg * Ftv + ig * tanh_fast(ftld);
      Fout[(size_t)row*256 + col] = ov;
      Fbf[(size_t)row*256 + col] = f2bf(ov);
    }
    if (c < 7) {
      short* Wn = Wst[(c+1) & 1];
      #pragma unroll
      for (int p = 0; p < 4; ++p) {
        int idx = (p*512 + tid) * 8;
        int row = idx >> 9, colk = idx & 511;
        *(float4*)&Wn[row*520 + colk] = pf[p];
      }
      __syncthreads();
    }
  }
}

// ---------- host ----------
extern "C" void kernel_launch(void* const* d_in, const int* in_sizes, int n_in,
                              void* d_out, int out_size, void* d_ws, size_t ws_size,
                              hipStream_t stream)
{
  (void)in_sizes; (void)n_in; (void)out_size; (void)ws_size;
  const float* wsi  = (const float*)d_in[0];
  const float* gen  = (const float*)d_in[1];
  const float* FT   = (const float*)d_in[2];
  const float* W_lr = (const float*)d_in[3];
  const float* b_lr = (const float*)d_in[4];
  const float* W_g  = (const float*)d_in[5];
  const float* b_g  = (const float*)d_in[6];
  const float* WqI  = (const float*)d_in[7];
  const float* WqG  = (const float*)d_in[8];
  const float* WkI  = (const float*)d_in[9];
  const float* WkG  = (const float*)d_in[10];
  const float* WvI  = (const float*)d_in[11];
  const float* WvG  = (const float*)d_in[12];
  const float* W1   = (const float*)d_in[13];
  const float* b1   = (const float*)d_in[14];
  const float* W2   = (const float*)d_in[15];
  const float* b2   = (const float*)d_in[16];
  const float* Wf   = (const float*)d_in[17];
  const float* bf   = (const float*)d_in[18];
  const float* Wi   = (const float*)d_in[19];
  const float* bi   = (const float*)d_in[20];
  const float* Vf   = (const float*)d_in[21];
  const float* Vi   = (const float*)d_in[22];
  const float* a_p  = (const float*)d_in[23];
  const float* b_p  = (const float*)d_in[24];

  float* out = (float*)d_out;
  float* ws  = (float*)d_ws;
  // fp32 region
  float* rr    = ws;                    // 256*256
  float* rW1   = rr    + 65536;         // 256*512
  float* rWf   = rW1   + 131072;
  float* rWi   = rWf   + 65536;
  float* qIp   = rWi   + 65536;
  float* qGp   = qIp   + 65536;
  float* lrf   = qGp   + 65536;         // 256*512
  float* gf    = lrf   + 131072;
  float* QI    = gf    + 131072;
  float* QG    = QI    + 65536;
  float* WkIt  = QG    + 65536;
  float* WkGt  = WkIt  + 65536;
  float* ftbI  = WkGt  + 65536;         // 256*256
  float* ftbG  = ftbI  + 65536;
  float* rt    = ftbG  + 65536;         // 256*1024
  // bf16 region
  unsigned short* A2   = (unsigned short*)(rt + 262144);   // 16384*512
  unsigned short* Gfb  = A2   + 8388608;                   // 16384*256
  unsigned short* Gib  = Gfb  + 4194304;                   // 16384*256
  unsigned short* Fbf  = Gib  + 4194304;                   // 16384*256
  unsigned short* FTbf = Fbf  + 4194304;                   // 64*256
  unsigned short* B1t  = FTbf + 16384;                     // 1024*256
  unsigned short* W2t  = B1t  + 262144;                    // 256*512

  k_convert<<<2112, 256, 0, stream>>>(W1, Vf, Vi, W2, FT, WkI, WkG,
                                      B1t, W2t, FTbf, WkIt, WkGt);
  k_pre_lin<<<32, 256, 0, stream>>>(wsi, gen, W_lr, b_lr, W_g, b_g, a_p, b_p, lrf, gf);
  k_pre_q<<<32, 256, 0, stream>>>(lrf, gf, WqI, WqG, QI, QG);
  k_pre_qp<<<32, 256, 0, stream>>>(QI, QG, WkIt, WkGt, qIp, qGp);

  // out[j] = F_{8-j}; step st produces F_{st+1} -> slot 7-st.
  const float* Fcur = nullptr;
  int bcast = 1;
  for (int st = 0; st < T_; ++st) {
    float* Fnext = out + (size_t)(7 - st) * NROW * D_;
    k_ftbar<<<256, 256, 0, stream>>>(bcast ? FTbf : Fbf, bcast, qIp, qGp, ftbI, ftbG);
    k_rt<<<64, 256, 0, stream>>>(ftbI, ftbG, WvI, WvG, rt);
    k_defuzz<<<256, 256, 0, stream>>>(rt, a_p, b_p, rr);
    k_rW<<<64, 256, 0, stream>>>(rr, W1, Wf, Wi, rW1, rWf, rWi);
    k_g1<<<256, 512, 0, stream>>>(bcast ? FTbf : Fbf, bcast, B1t,
                                  rW1, b1, rWf, bf, rWi, bi, A2, Gfb, Gib);
    k_g2<<<256, 512, 0, stream>>>(A2, W2t, b2, Fcur, FT, bcast, rr,
                                  Gfb, Gib, Fnext, Fbf);
    Fcur = Fnext;
    bcast = 0;
  }
}